// Round 1
// baseline (18231.812 us; speedup 1.0000x reference)
//
#include <hip/hip_runtime.h>
#include <stdint.h>

// Problem constants (match reference)
#define HID   2048
#define FEAT  1024
#define BATCH 256
#define TWARM 128
#define TSTEP 128
#define NOUT  (TSTEP + 1)   // 129
#define NBLK  256
#define NTHR  512

typedef short    v8s __attribute__((ext_vector_type(8)));   // 8 bf16 (bit pattern in shorts)
typedef float    v4f __attribute__((ext_vector_type(4)));
typedef uint32_t v4u __attribute__((ext_vector_type(4)));

// round-half-up f32 -> bf16 bits (statistically ~RNE, 1 add + 1 shift)
__device__ __forceinline__ uint32_t bf16_bits(float f) {
  union { float f; uint32_t u; } c; c.f = f;
  return (c.u + 0x8000u) >> 16;
}

// NOTE: guide-verified layouts for v_mfma_f32_16x16x32_bf16:
//   A frag: lane holds A[m = lane&15][k = (lane>>4)*8 + j], j=0..7
//   B frag: lane holds W[n = lane&15][k = (lane>>4)*8 + j]  (for out = A @ W^T)
//   D: lane holds D[row = (lane>>4)*4 + r][col = lane&15], r=0..3
__device__ __forceinline__ v4f mfma16(v8s a, v8s b, v4f c) {
  return __builtin_amdgcn_mfma_f32_16x16x32_bf16(a, b, c, 0, 0, 0);
}

__device__ __forceinline__ v8s ld8(const uint16_t* p) { return *(const v8s*)p; }

// fp32 x8 -> bf16 fragment (for warmup X in the K-tail)
__device__ __forceinline__ v8s a_from_f32(const float* p) {
  v4u x0 = *(const v4u*)p;
  v4u x1 = *(const v4u*)(p + 4);
  uint32_t r0 = __builtin_amdgcn_perm(x0.y + 0x8000u, x0.x + 0x8000u, 0x07060302u);
  uint32_t r1 = __builtin_amdgcn_perm(x0.w + 0x8000u, x0.z + 0x8000u, 0x07060302u);
  uint32_t r2 = __builtin_amdgcn_perm(x1.y + 0x8000u, x1.x + 0x8000u, 0x07060302u);
  uint32_t r3 = __builtin_amdgcn_perm(x1.w + 0x8000u, x1.z + 0x8000u, 0x07060302u);
  union { v4u u; v8s s; } c; c.u = (v4u){r0, r1, r2, r3};
  return c.s;
}

// ---------------------------------------------------------------------------
// Weight pack: W [N][K] fp32 row-major -> bf16 B-fragment chunks.
// chunk gid = (n_tile*(K/32) + k_tile)*64 + lane  (16 bytes each) holds
//   bf16(W[n_tile*16 + (lane&15)][k_tile*32 + (lane>>4)*8 + j]), j = 0..7
// Consumers then read chunk base + lane*16B: perfectly coalesced.
// ---------------------------------------------------------------------------
__global__ void pack_b(const float* __restrict__ W, uint32_t* __restrict__ out,
                       int K, int total_chunks) {
  int gid = blockIdx.x * blockDim.x + threadIdx.x;
  if (gid >= total_chunks) return;
  int lane = gid & 63, tile = gid >> 6;
  int k_tiles = K >> 5;
  int n_tile = tile / k_tiles;
  int k_tile = tile - n_tile * k_tiles;
  const float* src = W + (size_t)(n_tile * 16 + (lane & 15)) * K + k_tile * 32 + ((lane >> 4) * 8);
  uint32_t w0 = bf16_bits(src[0]) | (bf16_bits(src[1]) << 16);
  uint32_t w1 = bf16_bits(src[2]) | (bf16_bits(src[3]) << 16);
  uint32_t w2 = bf16_bits(src[4]) | (bf16_bits(src[5]) << 16);
  uint32_t w3 = bf16_bits(src[6]) | (bf16_bits(src[7]) << 16);
  *(v4u*)(out + (size_t)gid * 4) = (v4u){w0, w1, w2, w3};
}

// ---------------------------------------------------------------------------
// Grid barrier: monotonic counter in global ws (memset to 0 at launch).
// All 256 blocks are co-resident (grid == CU count). __threadfence() (agent
// acq_rel) emits buffer_wbl2/buffer_inv so h/pred writes are visible across
// the 8 non-coherent XCD L2s. LDS contents are unaffected by the invalidate.
// ---------------------------------------------------------------------------
__device__ __forceinline__ void grid_barrier(uint32_t* bar, uint32_t target) {
  __syncthreads();                 // all waves drain their own stores into L2
  if (threadIdx.x == 0) {
    __threadfence();               // release: write back dirty L2 -> LLC
    __hip_atomic_fetch_add(bar, 1u, __ATOMIC_RELAXED, __HIP_MEMORY_SCOPE_AGENT);
    while (__hip_atomic_load(bar, __ATOMIC_RELAXED, __HIP_MEMORY_SCOPE_AGENT) < target) {
      __builtin_amdgcn_s_sleep(2);
    }
    __threadfence();               // acquire: invalidate L1 + L2
  }
  __syncthreads();
}

// ---------------------------------------------------------------------------
// Persistent RNN kernel. Grid 256 x 512 threads (8 waves = 8 M-subtiles).
// Block (bt, nt): bt = batch half (128 rows), nt = 16-col slice of HID.
//   - W_hh slice (2048x16 bf16 = 64 KB) resident in LDS (packed order).
//   - warmup:  h' = relu(h @ Whh^T  +  x_t @ Wih^T + bias)     [1 phase/step]
//   - AR: fc (nt<64): pred = h @ Wfc^T + b_fc -> d_out + bf16 buffer
//         cell:       h' = relu(h @ Whh^T + pred @ Wih^T + bias)
// ---------------------------------------------------------------------------
__global__ __launch_bounds__(NTHR) void rnn_persistent(
    const float* __restrict__ X,
    const float* __restrict__ b_ih, const float* __restrict__ b_hh,
    const float* __restrict__ b_fc,
    const uint32_t* __restrict__ whh_p, const uint32_t* __restrict__ wih_p,
    const uint32_t* __restrict__ wfc_p,
    uint16_t* __restrict__ h0, uint16_t* __restrict__ h1,
    uint16_t* __restrict__ pred,
    float* __restrict__ out, uint32_t* __restrict__ bar)
{
  __shared__ uint32_t wlds[16384];           // exactly 64 KB

  const int bt   = blockIdx.x >> 7;          // 0..1
  const int nt   = blockIdx.x & 127;         // 0..127
  const int wave = threadIdx.x >> 6;         // 0..7  == m_sub
  const int lane = threadIdx.x & 63;
  const int quad = lane >> 4;
  const int l15  = lane & 15;

  // Load resident W_hh slice: 4096 chunks of 16 B at [nt*4096 ...]
  {
    const v4u* src = (const v4u*)whh_p + (size_t)nt * 4096;
    v4u* dst = (v4u*)wlds;
    for (int i = threadIdx.x; i < 4096; i += NTHR) dst[i] = src[i];
  }

  const int   ncol   = nt * 16 + l15;                    // hidden output col
  const float bias_c = b_ih[ncol] + b_hh[ncol];
  const int   fcol   = (nt < 64) ? nt * 16 + l15 : 0;    // fc output col
  const float bias_f = b_fc[fcol];
  __syncthreads();

  const int mrow_base = bt * 128 + wave * 16;  // wave's 16 batch rows
  const int arow      = mrow_base + l15;       // A-fragment row for this lane

  const uint16_t* lds_b = (const uint16_t*)wlds + lane * 8;          // + i*512
  const uint32_t* wih_base = wih_p + ((size_t)nt * 32) * 256 + lane * 4; // dwords: chunk*4
  const uint32_t* wfc_base = wfc_p + ((size_t)nt * 64) * 256 + lane * 4;

  uint32_t bar_t = 0;

  // ---------------- warmup ----------------
  for (int t = 0; t < TWARM; ++t) {
    const uint16_t* hc = (t & 1) ? h1 : h0;
    uint16_t*       hn = (t & 1) ? h0 : h1;
    v4f acc = {0.f, 0.f, 0.f, 0.f};
    if (t > 0) {
      const uint16_t* ha = hc + (size_t)arow * HID + quad * 8;
      #pragma unroll 8
      for (int i = 0; i < 64; ++i)
        acc = mfma16(ld8(ha + i * 32), ld8(lds_b + i * 512), acc);
    }
    {
      const float* xa = X + ((size_t)arow * TWARM + t) * FEAT + quad * 8;
      #pragma unroll 4
      for (int i = 0; i < 32; ++i)
        acc = mfma16(a_from_f32(xa + i * 32),
                     *(const v8s*)(wih_base + (size_t)i * 256), acc);
    }
    #pragma unroll
    for (int r = 0; r < 4; ++r) {
      float v = acc[r] + bias_c;
      v = v > 0.f ? v : 0.f;
      int row = mrow_base + quad * 4 + r;
      hn[(size_t)row * HID + ncol] = (uint16_t)bf16_bits(v);
    }
    grid_barrier(bar, bar_t += NBLK);
  }

  // ---------------- autoregressive ----------------
  uint16_t* hcur = h0;   // warmup ends (t=127 odd) writing h0
  uint16_t* hnxt = h1;
  for (int s = 0; s <= TSTEP; ++s) {
    // fc phase: pred_s = hcur @ Wfc^T + b_fc (blocks nt<64 cover 64 f-tiles)
    if (nt < 64) {
      v4f acc = {0.f, 0.f, 0.f, 0.f};
      const uint16_t* ha = hcur + (size_t)arow * HID + quad * 8;
      #pragma unroll 8
      for (int i = 0; i < 64; ++i)
        acc = mfma16(ld8(ha + i * 32),
                     *(const v8s*)(wfc_base + (size_t)i * 256), acc);
      #pragma unroll
      for (int r = 0; r < 4; ++r) {
        float v = acc[r] + bias_f;
        int row = mrow_base + quad * 4 + r;
        out[((size_t)row * NOUT + s) * FEAT + fcol] = v;
        pred[(size_t)row * FEAT + fcol] = (uint16_t)bf16_bits(v);
      }
    }
    grid_barrier(bar, bar_t += NBLK);
    if (s == TSTEP) break;

    // cell phase: hnxt = relu(hcur @ Whh^T + pred @ Wih^T + bias)
    v4f acc = {0.f, 0.f, 0.f, 0.f};
    {
      const uint16_t* ha = hcur + (size_t)arow * HID + quad * 8;
      #pragma unroll 8
      for (int i = 0; i < 64; ++i)
        acc = mfma16(ld8(ha + i * 32), ld8(lds_b + i * 512), acc);
    }
    {
      const uint16_t* pa = pred + (size_t)arow * FEAT + quad * 8;
      #pragma unroll 4
      for (int i = 0; i < 32; ++i)
        acc = mfma16(ld8(pa + i * 32),
                     *(const v8s*)(wih_base + (size_t)i * 256), acc);
    }
    #pragma unroll
    for (int r = 0; r < 4; ++r) {
      float v = acc[r] + bias_c;
      v = v > 0.f ? v : 0.f;
      int row = mrow_base + quad * 4 + r;
      hnxt[(size_t)row * HID + ncol] = (uint16_t)bf16_bits(v);
    }
    grid_barrier(bar, bar_t += NBLK);
    uint16_t* tmp = hcur; hcur = hnxt; hnxt = tmp;
  }
}

// ---------------------------------------------------------------------------
extern "C" void kernel_launch(void* const* d_in, const int* in_sizes, int n_in,
                              void* d_out, int out_size, void* d_ws, size_t ws_size,
                              hipStream_t stream) {
  const float* X    = (const float*)d_in[0];  // [256][128][1024]
  const float* Wih  = (const float*)d_in[1];  // [2048][1024]
  const float* bih  = (const float*)d_in[2];  // [2048]
  const float* Whh  = (const float*)d_in[3];  // [2048][2048]
  const float* bhh  = (const float*)d_in[4];  // [2048]
  const float* Wfc  = (const float*)d_in[5];  // [1024][2048]
  const float* bfc  = (const float*)d_in[6];  // [1024]
  float* out = (float*)d_out;

  // ws layout (~18.8 MB): barrier | h0 | h1 | pred | whh_p | wih_p | wfc_p
  char* ws = (char*)d_ws;
  uint32_t* bar  = (uint32_t*)ws;
  uint16_t* h0   = (uint16_t*)(ws + 256);
  uint16_t* h1   = h0 + (size_t)BATCH * HID;
  uint16_t* pred = h1 + (size_t)BATCH * HID;
  uint32_t* whh_p = (uint32_t*)(pred + (size_t)BATCH * FEAT);
  uint32_t* wih_p = whh_p + (size_t)HID * HID / 2;
  uint32_t* wfc_p = wih_p + (size_t)HID * FEAT / 2;

  hipMemsetAsync(bar, 0, 256, stream);

  // pack weights into B-fragment order (bf16)
  pack_b<<<(HID * HID / 8) / 256, 256, 0, stream>>>(Whh, whh_p, HID,  HID * HID / 8);
  pack_b<<<(HID * FEAT / 8) / 256, 256, 0, stream>>>(Wih, wih_p, FEAT, HID * FEAT / 8);
  pack_b<<<(FEAT * HID / 8) / 256, 256, 0, stream>>>(Wfc, wfc_p, HID,  FEAT * HID / 8);

  rnn_persistent<<<NBLK, NTHR, 0, stream>>>(X, bih, bhh, bfc,
                                            whh_p, wih_p, wfc_p,
                                            h0, h1, pred, out, bar);
}

// Round 2
// 14698.643 us; speedup vs baseline: 1.2404x; 1.2404x over previous
//
#include <hip/hip_runtime.h>
#include <stdint.h>

#define HID   2048
#define FEAT  1024
#define BATCH 256
#define TWARM 128
#define TSTEP 128
#define NOUT  129
#define NBLK  192
#define NTHR  512

typedef short    v8s __attribute__((ext_vector_type(8)));
typedef float    v4f __attribute__((ext_vector_type(4)));
typedef uint32_t v4u __attribute__((ext_vector_type(4)));
typedef int32_t  v4i __attribute__((ext_vector_type(4)));

// Device-scope buffer ops (SC[1:0]=2 -> bypass L1/L2, coherent at LLC).
// CPol: sc0=bit0, nt=bit1, sc1=bit4 on gfx940+.
#define AUX_SC1 16
__device__ v4i llvm_amdgcn_raw_buffer_load_i32x4(v4i srsrc, int voffset, int soffset, int aux) __asm("llvm.amdgcn.raw.buffer.load.v4i32");
__device__ void llvm_amdgcn_raw_buffer_store_i32x4(v4i data, v4i srsrc, int voffset, int soffset, int aux) __asm("llvm.amdgcn.raw.buffer.store.v4i32");

__device__ __forceinline__ v4i make_srd(const void* p) {
  union { const void* p; uint32_t w[2]; } c; c.p = p;
  v4i srd;
  srd.x = (int)c.w[0];
  srd.y = (int)c.w[1];
  srd.z = (int)0xFFFFFFFFu;   // disable bounds check
  srd.w = 0x00020000;         // raw untyped dword
  return srd;
}

__device__ __forceinline__ uint32_t bf16_bits(float f) {
  union { float f; uint32_t u; } c; c.f = f;
  return (c.u + 0x8000u) >> 16;
}

__device__ __forceinline__ v4f mfma16(v8s a, v8s b, v4f c) {
  return __builtin_amdgcn_mfma_f32_16x16x32_bf16(a, b, c, 0, 0, 0);
}

// fp32 x8 -> bf16 A-fragment (warmup X path)
__device__ __forceinline__ v8s a_from_f32(const float* p) {
  v4u x0 = *(const v4u*)p;
  v4u x1 = *(const v4u*)(p + 4);
  uint32_t r0 = __builtin_amdgcn_perm(x0.y + 0x8000u, x0.x + 0x8000u, 0x07060302u);
  uint32_t r1 = __builtin_amdgcn_perm(x0.w + 0x8000u, x0.z + 0x8000u, 0x07060302u);
  uint32_t r2 = __builtin_amdgcn_perm(x1.y + 0x8000u, x1.x + 0x8000u, 0x07060302u);
  uint32_t r3 = __builtin_amdgcn_perm(x1.w + 0x8000u, x1.z + 0x8000u, 0x07060302u);
  union { v4u u; v8s s; } c; c.u = (v4u){r0, r1, r2, r3};
  return c.s;
}

// ---------------------------------------------------------------------------
// pack_b: W [N][K] fp32 row-major -> bf16 fragment chunks (1 KB each).
// chunk (n_tile, k_tile): lane holds W[n_tile*16+(lane&15)][k_tile*32+(lane>>4)*8+j]
// ---------------------------------------------------------------------------
__global__ void pack_b(const float* __restrict__ W, uint32_t* __restrict__ out,
                       int K, int total_chunks) {
  int gid = blockIdx.x * blockDim.x + threadIdx.x;
  if (gid >= total_chunks) return;
  int lane = gid & 63, tile = gid >> 6;
  int k_tiles = K >> 5;
  int n_tile = tile / k_tiles;
  int k_tile = tile - n_tile * k_tiles;
  const float* src = W + (size_t)(n_tile * 16 + (lane & 15)) * K + k_tile * 32 + ((lane >> 4) * 8);
  uint32_t w0 = bf16_bits(src[0]) | (bf16_bits(src[1]) << 16);
  uint32_t w1 = bf16_bits(src[2]) | (bf16_bits(src[3]) << 16);
  uint32_t w2 = bf16_bits(src[4]) | (bf16_bits(src[5]) << 16);
  uint32_t w3 = bf16_bits(src[6]) | (bf16_bits(src[7]) << 16);
  *(v4u*)(out + (size_t)gid * 4) = (v4u){w0, w1, w2, w3};
}

// pack_bT: chunks of Wfc^T, i.e. B[h][f] = Wfc[f][h]. 128 h_tiles x 32 f_tiles.
__global__ void pack_bT(const float* __restrict__ Wfc, uint16_t* __restrict__ outp) {
  int gid = blockIdx.x * blockDim.x + threadIdx.x;   // chunk*64 + lane
  int lane = gid & 63, tile = gid >> 6;
  int h_tile = tile >> 5, f_tile = tile & 31;
  int f0 = f_tile * 32 + (lane >> 4) * 8;
  int h  = h_tile * 16 + (lane & 15);
  uint16_t* dst = outp + (size_t)tile * 512 + lane * 8;
  #pragma unroll
  for (int j = 0; j < 8; ++j)
    dst[j] = (uint16_t)bf16_bits(Wfc[(size_t)(f0 + j) * HID + h]);
}

// b_comb[n] = b_ih[n] + b_hh[n] + sum_f Wih[n][f] * b_fc[f].  One wave per n.
__global__ void bias_comb_k(const float* __restrict__ Wih, const float* __restrict__ b_ih,
                            const float* __restrict__ b_hh, const float* __restrict__ b_fc,
                            float* __restrict__ b_comb) {
  int wave = threadIdx.x >> 6, lane = threadIdx.x & 63;
  int n = blockIdx.x * 8 + wave;
  const float* wr = Wih + (size_t)n * FEAT;
  float s = 0.f;
  for (int f = lane; f < FEAT; f += 64) s += wr[f] * b_fc[f];
  for (int off = 32; off; off >>= 1) s += __shfl_down(s, off, 64);
  if (lane == 0) b_comb[n] = s + b_ih[n] + b_hh[n];
}

// ---------------------------------------------------------------------------
// comb_gemm: comb[n][h] = Whh[n][h] + sum_f Wih[n][f]*Wfc[f][h], written as
// bf16 fragment chunks (same layout as pack_b output). One wave per chunk.
// ---------------------------------------------------------------------------
__global__ __launch_bounds__(512) void comb_gemm(
    const uint16_t* __restrict__ wih_p, const uint16_t* __restrict__ wfcT_p,
    const float* __restrict__ Whh, uint16_t* __restrict__ comb_p)
{
  __shared__ uint16_t scratch[8][640];
  int wave = threadIdx.x >> 6, lane = threadIdx.x & 63;
  int quad = lane >> 4, l15 = lane & 15;
  int id = blockIdx.x * 8 + wave;     // 0..8191
  int n_tile = id >> 6;               // 0..127
  int k_tile = id & 63;               // h/32
  v4f acc0 = {0.f,0.f,0.f,0.f}, acc1 = {0.f,0.f,0.f,0.f};
  const uint16_t* A  = wih_p  + (size_t)n_tile * 32 * 512 + lane * 8;
  const uint16_t* B0 = wfcT_p + (size_t)(k_tile * 2) * 32 * 512 + lane * 8;
  const uint16_t* B1 = B0 + 32 * 512;
  #pragma unroll 8
  for (int f = 0; f < 32; ++f) {
    v8s a = *(const v8s*)(A + f * 512);
    acc0 = mfma16(a, *(const v8s*)(B0 + f * 512), acc0);
    acc1 = mfma16(a, *(const v8s*)(B1 + f * 512), acc1);
  }
  uint16_t* sc = &scratch[wave][0];
  #pragma unroll
  for (int r = 0; r < 4; ++r) {
    int n = n_tile * 16 + quad * 4 + r;
    int h = k_tile * 32 + l15;
    float v0 = acc0[r] + Whh[(size_t)n * HID + h];
    float v1 = acc1[r] + Whh[(size_t)n * HID + h + 16];
    sc[(quad*4+r)*40 + l15]      = (uint16_t)bf16_bits(v0);
    sc[(quad*4+r)*40 + 16 + l15] = (uint16_t)bf16_bits(v1);
  }
  v4u d = *(v4u*)(sc + l15 * 40 + quad * 8);
  *(v4u*)(comb_p + ((size_t)(n_tile * 64 + k_tile)) * 512 + lane * 8) = d;
}

// ---------------------------------------------------------------------------
// Grid barrier: arrival counter at LLC via agent-scope atomics. No cache
// maintenance needed: all mutable shared data moves with sc1 ops.
// ---------------------------------------------------------------------------
__device__ __forceinline__ void grid_barrier(uint32_t* bar, uint32_t target) {
  __syncthreads();                       // drains vmcnt/lgkmcnt
  if (threadIdx.x == 0) {
    __hip_atomic_fetch_add(bar, 1u, __ATOMIC_RELAXED, __HIP_MEMORY_SCOPE_AGENT);
    while (__hip_atomic_load(bar, __ATOMIC_RELAXED, __HIP_MEMORY_SCOPE_AGENT) < target) {
      __builtin_amdgcn_s_sleep(4);
    }
  }
  __syncthreads();
}

// Stage fill: copy 16 chunks (2 m_tiles x 8 k_tiles) of h into registers.
__device__ __forceinline__ void fill_issue(v4i srd, int rg, int s, int tid,
                                           v4i& p0, v4i& p1) {
  int voff0 = (((rg*2+0)*64 + s*8) << 10) + tid*16;
  int voff1 = (((rg*2+1)*64 + s*8) << 10) + tid*16;
  p0 = llvm_amdgcn_raw_buffer_load_i32x4(srd, voff0, 0, AUX_SC1);
  p1 = llvm_amdgcn_raw_buffer_load_i32x4(srd, voff1, 0, AUX_SC1);
}

// ---------------------------------------------------------------------------
// Persistent kernel. 192 blocks x 512 thr. block: cg = bid%24 (col-group of
// 128 cols over [comb | fc]), rg = bid/24 (32 rows). XCD = bid%8 = cg%8 ->
// same-cg blocks share one XCD's L2 for their weight slice.
// Wave w: m_sub = w&1 (16 rows), cpair = w>>1 (32 cols -> 2 MFMA tiles).
// h lives in A-fragment chunk format: chunk (m_tile 0..15, k_tile 0..63),
// 1 KB, lane-linear. All h traffic is sc1 (LLC-coherent).
// ---------------------------------------------------------------------------
__global__ __launch_bounds__(NTHR) void rnn_persistent(
    const float* __restrict__ X,
    const uint16_t* __restrict__ whh_p, const uint16_t* __restrict__ wih_p,
    const uint16_t* __restrict__ wfc_p, const uint16_t* __restrict__ comb_p,
    const float* __restrict__ b_comb, const float* __restrict__ b_fc,
    uint16_t* h0, uint16_t* h1,
    float* __restrict__ out, uint32_t* __restrict__ bar)
{
  __shared__ uint16_t abuf[2][8192];      // 2 x 16 KB A-stage
  __shared__ uint16_t scratch[8][640];    // per-wave D->A transpose bounce

  const int bid  = blockIdx.x;
  const int cg   = bid % 24;
  const int rg   = bid / 24;
  const int tid  = threadIdx.x;
  const int wave = tid >> 6;
  const int lane = tid & 63;
  const int quad = lane >> 4;
  const int l15  = lane & 15;
  const int m_sub = wave & 1;
  const int cpair = wave >> 1;

  const bool is_cell = (cg < 16);
  const int  fcg = cg - 16;
  const int  nt0 = (is_cell ? cg : fcg) * 8 + cpair * 2;

  float bias0, bias1;
  if (is_cell) {
    int c = cg * 128 + cpair * 32 + l15;
    bias0 = b_comb[c]; bias1 = b_comb[c + 16];
  } else {
    int c = fcg * 128 + cpair * 32 + l15;
    bias0 = b_fc[c];   bias1 = b_fc[c + 16];
  }

  const int m_tile     = rg * 2 + m_sub;
  const int k_tile_out = cg * 4 + cpair;         // cell h-chunk this wave writes
  uint16_t* sc = &scratch[wave][0];

  v4i srd_cur = make_srd(h0);
  v4i srd_nxt = make_srd(h1);

  uint32_t bar_t = 0;

  // ---------------- warmup: h' = relu(h@Whh^T + x_t@Wih^T + b_ih + b_hh) ----
  for (int t = 0; t < TWARM; ++t) {
    if (is_cell) {
      v4f acc0 = {0.f,0.f,0.f,0.f}, acc1 = {0.f,0.f,0.f,0.f};
      if (t > 0) {
        // staged K=2048 over h chunks
        v4i p0, p1;
        fill_issue(srd_cur, rg, 0, tid, p0, p1);
        *(v4i*)(&abuf[0][0] + tid*8) = p0;
        *(v4i*)(&abuf[0][4096] + tid*8) = p1;
        __syncthreads();
        for (int s = 0; s < 8; ++s) {
          v4i q0, q1;
          if (s < 7) fill_issue(srd_cur, rg, s+1, tid, q0, q1);
          const uint16_t* ab = &abuf[s&1][0] + m_sub*4096 + lane*8;
          const uint16_t* b0 = whh_p + ((size_t)nt0*64 + s*8)*512 + lane*8;
          const uint16_t* b1 = b0 + 64*512;
          #pragma unroll
          for (int kt = 0; kt < 8; ++kt) {
            v8s a = *(const v8s*)(ab + kt*512);
            acc0 = mfma16(a, *(const v8s*)(b0 + kt*512), acc0);
            acc1 = mfma16(a, *(const v8s*)(b1 + kt*512), acc1);
          }
          if (s < 7) {
            *(v4i*)(&abuf[(s+1)&1][0] + tid*8) = q0;
            *(v4i*)(&abuf[(s+1)&1][4096] + tid*8) = q1;
          }
          __syncthreads();
        }
      }
      // X part, K=1024 (normal cached loads; X is constant)
      {
        const float* xr = X + ((size_t)(rg*32 + m_sub*16 + l15) * TWARM + t) * FEAT + quad*8;
        const uint16_t* wb0 = wih_p + (size_t)nt0 * 32 * 512 + lane*8;
        const uint16_t* wb1 = wb0 + 32*512;
        #pragma unroll 4
        for (int ks = 0; ks < 32; ++ks) {
          v8s a = a_from_f32(xr + ks*32);
          acc0 = mfma16(a, *(const v8s*)(wb0 + ks*512), acc0);
          acc1 = mfma16(a, *(const v8s*)(wb1 + ks*512), acc1);
        }
      }
      // relu + bias, transpose to A-chunk, sc1 store
      #pragma unroll
      for (int r = 0; r < 4; ++r) {
        float v0 = acc0[r] + bias0; v0 = v0 > 0.f ? v0 : 0.f;
        float v1 = acc1[r] + bias1; v1 = v1 > 0.f ? v1 : 0.f;
        sc[(quad*4+r)*40 + l15]      = (uint16_t)bf16_bits(v0);
        sc[(quad*4+r)*40 + 16 + l15] = (uint16_t)bf16_bits(v1);
      }
      v4i d = *(v4i*)(sc + l15*40 + quad*8);
      llvm_amdgcn_raw_buffer_store_i32x4(d, srd_nxt,
          ((m_tile*64 + k_tile_out) << 10) + lane*16, 0, AUX_SC1);
    }
    grid_barrier(bar, bar_t += NBLK);
    v4i tmp = srd_cur; srd_cur = srd_nxt; srd_nxt = tmp;
  }

  // ---------------- AR: per step one phase: h' = relu(h@comb^T + b_comb)
  // (cell blocks) and out_s = h@Wfc^T + b_fc (fc blocks) -------------------
  for (int s_step = 0; s_step <= TSTEP; ++s_step) {
    const bool active = is_cell ? (s_step < TSTEP) : true;
    if (active) {
      const uint16_t* Bbase = is_cell ? comb_p : wfc_p;
      v4f acc0 = {0.f,0.f,0.f,0.f}, acc1 = {0.f,0.f,0.f,0.f};
      v4i p0, p1;
      fill_issue(srd_cur, rg, 0, tid, p0, p1);
      *(v4i*)(&abuf[0][0] + tid*8) = p0;
      *(v4i*)(&abuf[0][4096] + tid*8) = p1;
      __syncthreads();
      for (int s = 0; s < 8; ++s) {
        v4i q0, q1;
        if (s < 7) fill_issue(srd_cur, rg, s+1, tid, q0, q1);
        const uint16_t* ab = &abuf[s&1][0] + m_sub*4096 + lane*8;
        const uint16_t* b0 = Bbase + ((size_t)nt0*64 + s*8)*512 + lane*8;
        const uint16_t* b1 = b0 + 64*512;
        #pragma unroll
        for (int kt = 0; kt < 8; ++kt) {
          v8s a = *(const v8s*)(ab + kt*512);
          acc0 = mfma16(a, *(const v8s*)(b0 + kt*512), acc0);
          acc1 = mfma16(a, *(const v8s*)(b1 + kt*512), acc1);
        }
        if (s < 7) {
          *(v4i*)(&abuf[(s+1)&1][0] + tid*8) = q0;
          *(v4i*)(&abuf[(s+1)&1][4096] + tid*8) = q1;
        }
        __syncthreads();
      }
      if (is_cell) {
        #pragma unroll
        for (int r = 0; r < 4; ++r) {
          float v0 = acc0[r] + bias0; v0 = v0 > 0.f ? v0 : 0.f;
          float v1 = acc1[r] + bias1; v1 = v1 > 0.f ? v1 : 0.f;
          sc[(quad*4+r)*40 + l15]      = (uint16_t)bf16_bits(v0);
          sc[(quad*4+r)*40 + 16 + l15] = (uint16_t)bf16_bits(v1);
        }
        v4i d = *(v4i*)(sc + l15*40 + quad*8);
        llvm_amdgcn_raw_buffer_store_i32x4(d, srd_nxt,
            ((m_tile*64 + k_tile_out) << 10) + lane*16, 0, AUX_SC1);
      } else {
        #pragma unroll
        for (int r = 0; r < 4; ++r) {
          int row = rg*32 + m_sub*16 + quad*4 + r;
          float* o = out + ((size_t)row * NOUT + s_step) * FEAT + fcg*128 + cpair*32 + l15;
          o[0]  = acc0[r] + bias0;
          o[16] = acc1[r] + bias1;
        }
      }
    }
    if (s_step < TSTEP) {
      grid_barrier(bar, bar_t += NBLK);
      v4i tmp = srd_cur; srd_cur = srd_nxt; srd_nxt = tmp;
    }
  }
}

// ---------------------------------------------------------------------------
extern "C" void kernel_launch(void* const* d_in, const int* in_sizes, int n_in,
                              void* d_out, int out_size, void* d_ws, size_t ws_size,
                              hipStream_t stream) {
  const float* X   = (const float*)d_in[0];  // [256][128][1024]
  const float* Wih = (const float*)d_in[1];  // [2048][1024]
  const float* bih = (const float*)d_in[2];
  const float* Whh = (const float*)d_in[3];  // [2048][2048]
  const float* bhh = (const float*)d_in[4];
  const float* Wfc = (const float*)d_in[5];  // [1024][2048]
  const float* bfc = (const float*)d_in[6];
  float* out = (float*)d_out;

  // ws layout (bytes), ~30 MB total
  char* ws = (char*)d_ws;
  uint32_t* bar    = (uint32_t*)(ws + 0);
  uint16_t* h0     = (uint16_t*)(ws + 4096);
  uint16_t* h1     = (uint16_t*)(ws + 4096 + 1048576);
  uint16_t* whh_p  = (uint16_t*)(ws + 2101248);
  uint16_t* wih_p  = (uint16_t*)(ws + 10489856);
  uint16_t* wfc_p  = (uint16_t*)(ws + 14684160);
  uint16_t* wfcT_p = (uint16_t*)(ws + 18878464);
  uint16_t* comb_p = (uint16_t*)(ws + 23072768);
  float*    b_comb = (float*)(ws + 31461376);

  hipMemsetAsync(bar, 0, 4096, stream);

  pack_b<<<(HID*HID/8)/256, 256, 0, stream>>>(Whh, (uint32_t*)whh_p, HID,  HID*HID/8);
  pack_b<<<(HID*FEAT/8)/256, 256, 0, stream>>>(Wih, (uint32_t*)wih_p, FEAT, HID*FEAT/8);
  pack_b<<<(FEAT*HID/8)/256, 256, 0, stream>>>(Wfc, (uint32_t*)wfc_p, HID,  FEAT*HID/8);
  pack_bT<<<(FEAT*HID/8)/256, 256, 0, stream>>>(Wfc, wfcT_p);
  bias_comb_k<<<256, 512, 0, stream>>>(Wih, bih, bhh, bfc, b_comb);
  comb_gemm<<<1024, 512, 0, stream>>>(wih_p, wfcT_p, Whh, comb_p);

  rnn_persistent<<<NBLK, NTHR, 0, stream>>>(X, whh_p, wih_p, wfc_p, comb_p,
                                            b_comb, bfc, h0, h1, out, bar);
}